// Round 1
// 1361.671 us; speedup vs baseline: 1.0643x; 1.0643x over previous
//
#include <hip/hip_runtime.h>
#include <stdint.h>

// Problem constants (from reference setup_inputs)
#define B_  64
#define LA  512
#define LB  512
#define DD  768
#define NEGV -100000.0f

typedef __attribute__((ext_vector_type(8))) short bf16x8;
typedef __attribute__((ext_vector_type(4))) float f32x4;

__device__ __forceinline__ unsigned short f2bf(float x) {
    union { float f; unsigned u; } v; v.f = x;
    unsigned r = v.u + 0x7fffu + ((v.u >> 16) & 1u);   // RNE
    return (unsigned short)(r >> 16);
}
__device__ __forceinline__ float bf2f(unsigned short h) {
    union { float f; unsigned u; } v; v.u = ((unsigned)h) << 16;
    return v.f;
}

// global_load_lds: LDS dest is wave-uniform base + lane*16 (linear); global src per-lane.
#define GLD16(gp, lp) __builtin_amdgcn_global_load_lds( \
    (const __attribute__((address_space(1))) void*)(gp), \
    (__attribute__((address_space(3))) void*)(lp), 16, 0, 0)

// ---------------------------------------------------------------------------
// prep: x [B,L,DD] fp32 ->
//   xT  [B,DD,L] bf16 (hi), XOR-swizzled cols  (PV V-operand)
//   xh/xl [B,L,DD] bf16 hi/lo, XOR-swizzled cols (egemm operands)
// Swizzle: within each 32-elem chunk, 8-elem group q stored at q ^ ((row>>1)&3).
// Makes linear global_load_lds staging land bank-conflict-free for swizzled
// ds_read_b128 fragment reads (2-way aliasing only = free).
// grid (L/64, DD/64, B), block 256
// ---------------------------------------------------------------------------
template<int L>
__global__ void prep_k(const float* __restrict__ x,
                       unsigned short* __restrict__ xT,
                       unsigned short* __restrict__ xh,
                       unsigned short* __restrict__ xl) {
    __shared__ unsigned short tile[64][65];
    const int l0 = blockIdx.x * 64, d0 = blockIdx.y * 64, b = blockIdx.z;
    const float* xp = x + (size_t)b * L * DD;
    unsigned short* tp = xT + (size_t)b * DD * L;
    unsigned short* hp = xh + (size_t)b * L * DD;
    unsigned short* lp = xl + (size_t)b * L * DD;
    const int c4 = (threadIdx.x & 15) * 4;   // 0..60 step 4
    const int r0 = threadIdx.x >> 4;         // 0..15
#pragma unroll
    for (int s = 0; s < 4; ++s) {
        const int r = r0 + s * 16;
        const int l = l0 + r;
        float4 v = *(const float4*)(xp + (size_t)l * DD + d0 + c4);
        ushort4 h, lo;
        h.x = f2bf(v.x); lo.x = f2bf(v.x - bf2f(h.x));
        h.y = f2bf(v.y); lo.y = f2bf(v.y - bf2f(h.y));
        h.z = f2bf(v.z); lo.z = f2bf(v.z - bf2f(h.z));
        h.w = f2bf(v.w); lo.w = f2bf(v.w - bf2f(h.w));
        tile[r][c4 + 0] = h.x; tile[r][c4 + 1] = h.y;
        tile[r][c4 + 2] = h.z; tile[r][c4 + 3] = h.w;
        const int qp = (((c4 >> 3) ^ (r >> 1)) & 3) << 3;
        const int dp = d0 + (c4 & ~31) + qp + (c4 & 7);
        *(ushort4*)&hp[(size_t)l * DD + dp] = h;
        *(ushort4*)&lp[(size_t)l * DD + dp] = lo;
    }
    __syncthreads();
    const int c = threadIdx.x & 63, rr = threadIdx.x >> 6;
#pragma unroll
    for (int s = 0; s < 16; ++s) {
        const int r = rr + s * 4;                       // row of xT = d-index
        const int qp = (((c >> 3) ^ (r >> 1)) & 3) << 3;
        const int cp = l0 + (c & ~31) + qp + (c & 7);   // swizzled l-index
        tp[(size_t)(d0 + r) * L + cp] = tile[c][r];
    }
}

// ---------------------------------------------------------------------------
// e = a . b^T  (bf16x3 split, fp32-accurate); operands pre-split+pre-swizzled.
// Pure global_load_lds staging (zero VALU in K-loop).
// grid (128, 8) 1D-decoded: all 16 tiles of a batch on one XCD.
// ---------------------------------------------------------------------------
__global__ __launch_bounds__(256, 2)
void egemm_k(const unsigned short* __restrict__ Ahg, const unsigned short* __restrict__ Alg,
             const unsigned short* __restrict__ Bhg, const unsigned short* __restrict__ Blg,
             const int* __restrict__ mask_a, const int* __restrict__ mask_b,
             float* __restrict__ e) {
    __shared__ unsigned short Ah[128 * 32], Al[128 * 32], Bh[128 * 32], Bl[128 * 32];
    const int loc = blockIdx.x, g = blockIdx.y;
    const int t = loc >> 3;
    const int bb = g * 8 + (loc & 7);          // xcd = loc&7 -> batch-grouped
    const int m0 = (t & 3) * 128, n0 = (t >> 2) * 128;

    const int tid = threadIdx.x;
    const int lane = tid & 63, w = tid >> 6;
    const int wm = (w >> 1) * 64, wn = (w & 1) * 64;
    const int lrow = lane & 15, qsel = lane >> 4;
    const int poff = ((qsel ^ (lrow >> 1)) & 3) << 3;   // swizzled 16B-slot

    const size_t boff = (size_t)bb * 512 * DD;
    const int sr0 = (2 * w) * 16 + (lane >> 2);   // staging row, inst j=2w
    const int sc = (lane & 3) * 8;                // staging 16B slot
    const unsigned short* pa0 = Ahg + boff + (size_t)(m0 + sr0) * DD + sc;
    const unsigned short* pa1 = pa0 + 16 * DD;
    const unsigned short* pl0 = Alg + boff + (size_t)(m0 + sr0) * DD + sc;
    const unsigned short* pl1 = pl0 + 16 * DD;
    const unsigned short* pb0 = Bhg + boff + (size_t)(n0 + sr0) * DD + sc;
    const unsigned short* pb1 = pb0 + 16 * DD;
    const unsigned short* pm0 = Blg + boff + (size_t)(n0 + sr0) * DD + sc;
    const unsigned short* pm1 = pm0 + 16 * DD;
    unsigned short* la0 = &Ah[(2 * w) * 512]; unsigned short* la1 = la0 + 512;
    unsigned short* ll0 = &Al[(2 * w) * 512]; unsigned short* ll1 = ll0 + 512;
    unsigned short* lb0 = &Bh[(2 * w) * 512]; unsigned short* lb1 = lb0 + 512;
    unsigned short* lm0 = &Bl[(2 * w) * 512]; unsigned short* lm1 = lm0 + 512;

    f32x4 acc[4][4] = {};

    for (int k0 = 0; k0 < DD; k0 += 32) {
        GLD16(pa0 + k0, la0); GLD16(pa1 + k0, la1);
        GLD16(pl0 + k0, ll0); GLD16(pl1 + k0, ll1);
        GLD16(pb0 + k0, lb0); GLD16(pb1 + k0, lb1);
        GLD16(pm0 + k0, lm0); GLD16(pm1 + k0, lm1);
        __syncthreads();                 // vmcnt(0) drain + barrier: LDS ready
        bf16x8 ahf[4], alf[4], bhf[4], blf[4];
#pragma unroll
        for (int mi = 0; mi < 4; ++mi) {
            const int R = wm + mi * 16 + lrow;
            ahf[mi] = *(const bf16x8*)&Ah[R * 32 + poff];
            alf[mi] = *(const bf16x8*)&Al[R * 32 + poff];
        }
#pragma unroll
        for (int ni = 0; ni < 4; ++ni) {
            const int R = wn + ni * 16 + lrow;
            bhf[ni] = *(const bf16x8*)&Bh[R * 32 + poff];
            blf[ni] = *(const bf16x8*)&Bl[R * 32 + poff];
        }
#pragma unroll
        for (int mi = 0; mi < 4; ++mi)
#pragma unroll
            for (int ni = 0; ni < 4; ++ni) {
                acc[mi][ni] = __builtin_amdgcn_mfma_f32_16x16x32_bf16(alf[mi], bhf[ni], acc[mi][ni], 0, 0, 0);
                acc[mi][ni] = __builtin_amdgcn_mfma_f32_16x16x32_bf16(ahf[mi], blf[ni], acc[mi][ni], 0, 0, 0);
                acc[mi][ni] = __builtin_amdgcn_mfma_f32_16x16x32_bf16(ahf[mi], bhf[ni], acc[mi][ni], 0, 0, 0);
            }
        __syncthreads();                 // all waves done reading before next stage
    }

    const int* map = mask_a + bb * LA;
    const int* mbp = mask_b + bb * LB;
    float* ep = e + (size_t)bb * LA * LB;
    const int colbase = n0 + wn + (lane & 15);
    const int rowbase = m0 + wm + (lane >> 4) * 4;
#pragma unroll
    for (int mi = 0; mi < 4; ++mi)
#pragma unroll
        for (int ni = 0; ni < 4; ++ni) {
            const int j = colbase + ni * 16;
            const float mbf = (float)mbp[j];
#pragma unroll
            for (int r = 0; r < 4; ++r) {
                const int i = rowbase + mi * 16 + r;
                const float mm = (float)map[i] * mbf;
                const float v = (mm < 0.5f) ? NEGV : acc[mi][ni][r];
                __builtin_nontemporal_store(v, &ep[(size_t)i * LB + j]);
            }
        }
}

// ---------------------------------------------------------------------------
// Row softmax stats (axis=2): one wave per row. Unchanged.
// ---------------------------------------------------------------------------
__global__ void rowstats_k(const float* __restrict__ e,
                           float* __restrict__ rmax, float* __restrict__ rinv) {
    const int row = blockIdx.x * 4 + (threadIdx.x >> 6);
    const int lane = threadIdx.x & 63;
    const float* ep = e + (size_t)row * LB;
    float4 v1 = *(const float4*)(ep + lane * 8);
    float4 v2 = *(const float4*)(ep + lane * 8 + 4);
    float m = fmaxf(fmaxf(fmaxf(v1.x, v1.y), fmaxf(v1.z, v1.w)),
                    fmaxf(fmaxf(v2.x, v2.y), fmaxf(v2.z, v2.w)));
#pragma unroll
    for (int o = 32; o; o >>= 1) m = fmaxf(m, __shfl_xor(m, o));
    float s = __expf(v1.x - m) + __expf(v1.y - m) + __expf(v1.z - m) + __expf(v1.w - m)
            + __expf(v2.x - m) + __expf(v2.y - m) + __expf(v2.z - m) + __expf(v2.w - m);
#pragma unroll
    for (int o = 32; o; o >>= 1) s += __shfl_xor(s, o);
    if (lane == 0) { rmax[row] = m; rinv[row] = 1.0f / s; }
}

// ---------------------------------------------------------------------------
// Column softmax stats (axis=1): single-pass online, 4 row-segments/column
// merged through LDS. grid (LB/64, B), block 256.
// ---------------------------------------------------------------------------
__global__ void colstats_k(const float* __restrict__ e,
                           float* __restrict__ cmax, float* __restrict__ cinv) {
    __shared__ float sm[4][64], ss[4][64];
    const int j0 = blockIdx.x * 64;
    const int bb = blockIdx.y;
    const int jj = threadIdx.x & 63, seg = threadIdx.x >> 6;
    const float* ep = e + (size_t)bb * LA * LB + (size_t)seg * 128 * LB + j0 + jj;
    float m = -3.4e38f, s = 0.f;
    for (int i = 0; i < 128; ++i) {
        const float v = ep[(size_t)i * LB];
        const float nm = fmaxf(m, v);
        s = s * __expf(m - nm) + __expf(v - nm);
        m = nm;
    }
    sm[seg][jj] = m; ss[seg][jj] = s;
    __syncthreads();
    if (seg == 0) {
        const float m0 = sm[0][jj], m1 = sm[1][jj], m2 = sm[2][jj], m3 = sm[3][jj];
        const float M = fmaxf(fmaxf(m0, m1), fmaxf(m2, m3));
        const float S = ss[0][jj] * __expf(m0 - M) + ss[1][jj] * __expf(m1 - M)
                      + ss[2][jj] * __expf(m2 - M) + ss[3][jj] * __expf(m3 - M);
        cmax[bb * LB + j0 + jj] = M;
        cinv[bb * LB + j0 + jj] = 1.0f / S;
    }
}

// ---------------------------------------------------------------------------
// P generation: Pa (softmax axis2) and PbT (softmax axis1, transposed), bf16,
// written in the XOR-swizzled layout consumed by pv_gemm's global_load_lds.
// grid (LA/64, LB/64, B), block 256
// ---------------------------------------------------------------------------
__global__ void pgen_k(const float* __restrict__ e,
                       const float* __restrict__ rmax, const float* __restrict__ rinv,
                       const float* __restrict__ cmax, const float* __restrict__ cinv,
                       unsigned short* __restrict__ Pa, unsigned short* __restrict__ PbT) {
    __shared__ unsigned short tile[64][65];
    const int i0 = blockIdx.x * 64, j0 = blockIdx.y * 64, bb = blockIdx.z;
    const float* ep = e + (size_t)bb * LA * LB;
    const int c = threadIdx.x & 63, r0 = threadIdx.x >> 6;
    const float cm = cmax[bb * LB + j0 + c];
    const float ci = cinv[bb * LB + j0 + c];
#pragma unroll
    for (int s = 0; s < 16; ++s) {
        const int r = r0 + s * 4;
        const float rm = rmax[bb * LA + i0 + r];
        const float ri = rinv[bb * LA + i0 + r];
        const float v = ep[(size_t)(i0 + r) * LB + j0 + c];
        const int qp = (((c >> 3) ^ (r >> 1)) & 3) << 3;
        const int jp = j0 + (c & ~31) + qp + (c & 7);
        Pa[((size_t)bb * LA + i0 + r) * LB + jp] = f2bf(__expf(v - rm) * ri);
        tile[r][c] = f2bf(__expf(v - cm) * ci);
    }
    __syncthreads();
#pragma unroll
    for (int s = 0; s < 16; ++s) {
        const int r = r0 + s * 4;                       // row of PbT = j-index
        const int qp = (((c >> 3) ^ (r >> 1)) & 3) << 3;
        const int ip = i0 + (c & ~31) + qp + (c & 7);   // swizzled i-index
        PbT[((size_t)bb * LB + j0 + r) * LA + ip] = tile[c][r];
    }
}

// ---------------------------------------------------------------------------
// t = P . V with fused concat epilogue. P [B,512,512], VT [B,DD,512] both
// swizzled bf16; pure global_load_lds staging. grid (192, 8) batch-grouped.
// ---------------------------------------------------------------------------
__global__ __launch_bounds__(256, 2)
void pv_gemm_k(const unsigned short* __restrict__ P,
               const unsigned short* __restrict__ VT,
               const float* __restrict__ X,
               float* __restrict__ out) {
    constexpr int K = 512;
    __shared__ unsigned short At[128 * 32], Bt[128 * 32];
    const int loc = blockIdx.x, g = blockIdx.y;
    const int t = loc >> 3;
    const int bb = g * 8 + (loc & 7);
    const int m0 = (t & 3) * 128, n0 = (t >> 2) * 128;   // 4 x 6 tiles

    const int tid = threadIdx.x;
    const int lane = tid & 63, w = tid >> 6;
    const int wm = (w >> 1) * 64, wn = (w & 1) * 64;
    const int lrow = lane & 15, qsel = lane >> 4;
    const int poff = ((qsel ^ (lrow >> 1)) & 3) << 3;

    const unsigned short* Pp = P + (size_t)bb * 512 * K;
    const unsigned short* Vp = VT + (size_t)bb * DD * K;
    const int sr0 = (2 * w) * 16 + (lane >> 2);
    const int sc = (lane & 3) * 8;
    const unsigned short* p0 = Pp + (size_t)(m0 + sr0) * K + sc;
    const unsigned short* p1 = p0 + 16 * K;
    const unsigned short* v0 = Vp + (size_t)(n0 + sr0) * K + sc;
    const unsigned short* v1 = v0 + 16 * K;
    unsigned short* lA0 = &At[(2 * w) * 512]; unsigned short* lA1 = lA0 + 512;
    unsigned short* lB0 = &Bt[(2 * w) * 512]; unsigned short* lB1 = lB0 + 512;

    f32x4 acc[4][4] = {};
    for (int k0 = 0; k0 < K; k0 += 32) {
        GLD16(p0 + k0, lA0); GLD16(p1 + k0, lA1);
        GLD16(v0 + k0, lB0); GLD16(v1 + k0, lB1);
        __syncthreads();
        bf16x8 af[4], bf_[4];
#pragma unroll
        for (int mi = 0; mi < 4; ++mi)
            af[mi] = *(const bf16x8*)&At[(wm + mi * 16 + lrow) * 32 + poff];
#pragma unroll
        for (int ni = 0; ni < 4; ++ni)
            bf_[ni] = *(const bf16x8*)&Bt[(wn + ni * 16 + lrow) * 32 + poff];
#pragma unroll
        for (int mi = 0; mi < 4; ++mi)
#pragma unroll
            for (int ni = 0; ni < 4; ++ni)
                acc[mi][ni] = __builtin_amdgcn_mfma_f32_16x16x32_bf16(af[mi], bf_[ni], acc[mi][ni], 0, 0, 0);
        __syncthreads();
    }

    const float* Xp = X + (size_t)bb * 512 * DD;
    float* op = out + (size_t)bb * 512 * (4 * DD);
    const int colbase = n0 + wn + (lane & 15);
    const int rowbase = m0 + wm + (lane >> 4) * 4;
#pragma unroll
    for (int mi = 0; mi < 4; ++mi)
#pragma unroll
        for (int ni = 0; ni < 4; ++ni) {
            const int d = colbase + ni * 16;
#pragma unroll
            for (int r = 0; r < 4; ++r) {
                const int i = rowbase + mi * 16 + r;
                const float tv = acc[mi][ni][r];
                const float xv = Xp[(size_t)i * DD + d];
                float* o = op + (size_t)i * (4 * DD) + d;
                __builtin_nontemporal_store(xv, o);
                __builtin_nontemporal_store(tv, o + DD);
                __builtin_nontemporal_store(xv - tv, o + 2 * DD);
                __builtin_nontemporal_store(xv * tv, o + 3 * DD);
            }
        }
}

// ---------------------------------------------------------------------------
extern "C" void kernel_launch(void* const* d_in, const int* in_sizes, int n_in,
                              void* d_out, int out_size, void* d_ws, size_t ws_size,
                              hipStream_t stream) {
    const float* a      = (const float*)d_in[0];
    const int*   mask_a = (const int*)d_in[1];
    const float* b      = (const float*)d_in[2];
    const int*   mask_b = (const int*)d_in[3];
    float* out = (float*)d_out;

    uint8_t* w = (uint8_t*)d_ws;
    float* e            = (float*)w;          w += (size_t)B_ * LA * LB * 4;   // 67.1 MB
    unsigned short* aT  = (unsigned short*)w; w += (size_t)B_ * DD * LA * 2;   // 50.3 MB
    unsigned short* bT  = (unsigned short*)w; w += (size_t)B_ * DD * LB * 2;   // 50.3 MB
    unsigned short* ahi = (unsigned short*)w; w += (size_t)B_ * LA * DD * 2;   // 50.3 MB
    unsigned short* alo = (unsigned short*)w; w += (size_t)B_ * LA * DD * 2;   // 50.3 MB
    unsigned short* bhi = (unsigned short*)w; w += (size_t)B_ * LB * DD * 2;   // 50.3 MB
    unsigned short* blo = (unsigned short*)w; w += (size_t)B_ * LB * DD * 2;   // 50.3 MB
    float* rmax = (float*)w; w += (size_t)B_ * LA * 4;
    float* rinv = (float*)w; w += (size_t)B_ * LA * 4;
    float* cmax = (float*)w; w += (size_t)B_ * LB * 4;
    float* cinv = (float*)w; w += (size_t)B_ * LB * 4;
    // Pa/PbT alias the hi/lo block (dead after egemm; stream-ordered safe)
    unsigned short* Pa  = ahi;                              // 33.6 MB
    unsigned short* PbT = ahi + (size_t)B_ * LA * LB;       // 33.6 MB (into alo)
    // peak workspace ~370 MB

    prep_k<LA><<<dim3(LA / 64, DD / 64, B_), 256, 0, stream>>>(a, aT, ahi, alo);
    prep_k<LB><<<dim3(LB / 64, DD / 64, B_), 256, 0, stream>>>(b, bT, bhi, blo);
    egemm_k<<<dim3(128, 8), 256, 0, stream>>>(ahi, alo, bhi, blo, mask_a, mask_b, e);
    rowstats_k<<<B_ * LA / 4, 256, 0, stream>>>(e, rmax, rinv);
    colstats_k<<<dim3(LB / 64, B_), 256, 0, stream>>>(e, cmax, cinv);
    pgen_k<<<dim3(LA / 64, LB / 64, B_), 256, 0, stream>>>(e, rmax, rinv, cmax, cinv, Pa, PbT);
    float* out_mb = out + (size_t)B_ * LA * (4 * DD);
    pv_gemm_k<<<dim3(192, 8), 256, 0, stream>>>(Pa, bT, a, out);
    pv_gemm_k<<<dim3(192, 8), 256, 0, stream>>>(PbT, aT, b, out_mb);
}